// Round 2
// baseline (10724.182 us; speedup 1.0000x reference)
//
#include <hip/hip_runtime.h>
#include <hip/hip_bf16.h>

using bf16 = __hip_bfloat16;
using short8 = __attribute__((ext_vector_type(8))) short;
using f32x4 = __attribute__((ext_vector_type(4))) float;

#define BB 512
#define HH 1024
#define DD 64
#define TT 96

__device__ __forceinline__ void load_lds16(const void* g, void* l) {
  __builtin_amdgcn_global_load_lds(
      (const __attribute__((address_space(1))) unsigned int*)g,
      (__attribute__((address_space(3))) unsigned int*)l, 16, 0, 0);
}

__device__ __forceinline__ float sigm(float x) { return 1.0f / (1.0f + __expf(-x)); }
__device__ __forceinline__ float tanh_f(float x) {
  float e = __expf(2.0f * x);
  return 1.0f - 2.0f / (e + 1.0f);
}
__device__ __forceinline__ float wred(float v) {
#pragma unroll
  for (int m = 1; m < 64; m <<= 1) v += __shfl_xor(v, m, 64);
  return v;
}

// ---------------- preprocessing kernels ----------------

__global__ __launch_bounds__(256) void init_states_k(
    const float* __restrict__ x0, const float* __restrict__ hn, const float* __restrict__ cn,
    bf16* __restrict__ xbh, bf16* __restrict__ xbl,
    bf16* __restrict__ h0h, bf16* __restrict__ h0l,
    bf16* __restrict__ h1h, bf16* __restrict__ h1l,
    float* __restrict__ c0, float* __restrict__ c1)
{
  int i = blockIdx.x * 256 + threadIdx.x;
  if (i < BB * HH) {
    float v0 = hn[i];
    bf16 a0 = __float2bfloat16(v0);
    h0h[i] = a0; h0l[i] = __float2bfloat16(v0 - __bfloat162float(a0));
    float v1 = hn[BB * HH + i];
    bf16 a1 = __float2bfloat16(v1);
    h1h[i] = a1; h1l[i] = __float2bfloat16(v1 - __bfloat162float(a1));
    c0[i] = cn[i];
    c1[i] = cn[BB * HH + i];
  }
  if (i < BB * DD) {
    float v = x0[i];
    bf16 a = __float2bfloat16(v);
    xbh[i] = a; xbl[i] = __float2bfloat16(v - __bfloat162float(a));
  }
}

// gate-row permutation: col c (= g*1024 + n) -> pr = (n>>5)*128 + g*32 + (n&31)
__device__ __forceinline__ int gate_perm(int c) {
  int g = c >> 10, n = c & 1023;
  return (n >> 5) * 128 + g * 32 + (n & 31);
}

// builds W0t rows for k<64 (folded emb_W @ W_ih0) + bias0
__global__ __launch_bounds__(256) void fold_emb_k(
    const float* __restrict__ embW, const float* __restrict__ embB,
    const float* __restrict__ Wih0, const float* __restrict__ bih0, const float* __restrict__ bhh0,
    bf16* __restrict__ W0h, bf16* __restrict__ W0l, float* __restrict__ bias0)
{
  __shared__ float sW[512 * 8];
  __shared__ float sb[512];
  int tid = threadIdx.x;
  int d0 = blockIdx.y * 8;
  for (int i = tid; i < 4096; i += 256) {
    int j = i >> 9;
    int e = i & 511;
    sW[e * 8 + j] = embW[(size_t)(d0 + j) * 512 + e];
  }
  for (int i = tid; i < 512; i += 256) sb[i] = embB[i];
  __syncthreads();
  int c = blockIdx.x * 256 + tid;  // 0..4095
  float acc[8] = {0, 0, 0, 0, 0, 0, 0, 0};
  float bacc = 0.0f;
  for (int e = 0; e < 512; ++e) {
    float wv = Wih0[(size_t)e * 4096 + c];
    float4 wa = *(const float4*)&sW[e * 8];
    float4 wb = *(const float4*)&sW[e * 8 + 4];
    acc[0] += wa.x * wv; acc[1] += wa.y * wv; acc[2] += wa.z * wv; acc[3] += wa.w * wv;
    acc[4] += wb.x * wv; acc[5] += wb.y * wv; acc[6] += wb.z * wv; acc[7] += wb.w * wv;
    bacc += sb[e] * wv;
  }
  int pr = gate_perm(c);
#pragma unroll
  for (int j = 0; j < 8; ++j) {
    float v = acc[j];
    bf16 h = __float2bfloat16(v);
    W0h[(size_t)pr * 1088 + d0 + j] = h;
    W0l[(size_t)pr * 1088 + d0 + j] = __float2bfloat16(v - __bfloat162float(h));
  }
  if (blockIdx.y == 0) bias0[pr] = bacc + bih0[c] + bhh0[c];
}

// src f32 [K][N] row-major -> dst bf16 hi/lo [perm(c)][dstStride] at col offset k0
template <bool PERM>
__global__ __launch_bounds__(256) void transpose_conv_k(
    const float* __restrict__ src, int N,
    bf16* __restrict__ dsth, bf16* __restrict__ dstl, int dstStride, int k0)
{
  __shared__ float tb[32][33];
  int tx = threadIdx.x & 31;
  int ty = threadIdx.x >> 5;  // 0..7
  int c0 = blockIdx.x * 32;
  int kk0 = blockIdx.y * 32;
#pragma unroll
  for (int q = 0; q < 4; ++q) {
    int k = kk0 + q * 8 + ty;
    tb[q * 8 + ty][tx] = src[(size_t)k * N + c0 + tx];
  }
  __syncthreads();
#pragma unroll
  for (int q = 0; q < 4; ++q) {
    int cc = c0 + q * 8 + ty;
    int pr = PERM ? gate_perm(cc) : cc;
    float v = tb[tx][q * 8 + ty];
    bf16 h = __float2bfloat16(v);
    size_t di = (size_t)pr * dstStride + k0 + kk0 + tx;
    dsth[di] = h;
    dstl[di] = __float2bfloat16(v - __bfloat162float(h));
  }
}

__global__ __launch_bounds__(256) void bias_perm_k(
    const float* __restrict__ a, const float* __restrict__ b, float* __restrict__ out)
{
  int c = blockIdx.x * 256 + threadIdx.x;
  out[gate_perm(c)] = a[c] + b[c];
}

// ---------------- main GEMM (+ optional LSTM-cell epilogue), hi/lo split ----------------
// C tile 64x128, 4 waves split-M (16x128 each), BK=32, dbuf LDS (48KB).
// acc += Ah*Bh + Ah*Bl + Al*Bh  (Al*Bl ~1.6e-5 rel, dropped).
// EPI==0: gate panel [i32|f32|g32|o32] of 32 units -> cell -> h hi/lo out, c inplace f32.
// EPI==1: f32 + bias -> zout.
template <int EPI>
__global__ __launch_bounds__(256) void gemm_step_k(
    const bf16* __restrict__ A1h, const bf16* __restrict__ A1l, int lda1, int K1len,
    const bf16* __restrict__ A2h, const bf16* __restrict__ A2l, int lda2,
    const bf16* __restrict__ Bth, const bf16* __restrict__ Btl, int KTOT,
    const float* __restrict__ bias,
    float* __restrict__ zout,
    float* __restrict__ cstate,
    bf16* __restrict__ houth, bf16* __restrict__ houtl,
    int nPanels)
{
  // per buffer: Ah 4K | Al 4K | Bh 8K | Bl 8K = 24KB; x2 buffers = 48KB
  __shared__ __align__(16) char smem[49152];
  const int tid = threadIdx.x;
  const int lane = tid & 63;
  const int wv = tid >> 6;
  const int bid = blockIdx.x;
  const int npanel = bid % nPanels;  // n fastest: neighbor blocks share B panel (L2)
  const int m0 = (bid / nPanels) * 64;
  const int nrow0 = npanel * 128;

  f32x4 acc[8] = {};
  const int ntiles = KTOT >> 5;

  auto stage = [&](int qbuf, int kt) {
    char* lb = smem + qbuf * 24576;
    {
      int row = tid >> 2, sl = tid & 3;                 // A: 64 rows x 4 slots
      int sb = (sl * 16) ^ (((row >> 2) & 3) << 4);     // pre-swizzled source byte
      int ke = kt + (sb >> 1);
      const bf16 *gh, *gl;
      if (kt < K1len) {
        gh = A1h + (size_t)(m0 + row) * lda1 + ke;
        gl = A1l + (size_t)(m0 + row) * lda1 + ke;
      } else {
        gh = A2h + (size_t)(m0 + row) * lda2 + (ke - K1len);
        gl = A2l + (size_t)(m0 + row) * lda2 + (ke - K1len);
      }
      load_lds16((const void*)gh, (void*)(lb + tid * 16));
      load_lds16((const void*)gl, (void*)(lb + 4096 + tid * 16));
    }
#pragma unroll
    for (int q = 0; q < 2; ++q) {                       // B: 128 rows x 4 slots
      int L = q * 256 + tid;
      int row = L >> 2, sl = L & 3;
      int sb = (sl * 16) ^ (((row >> 2) & 3) << 4);
      int ke = kt + (sb >> 1);
      load_lds16((const void*)(Bth + (size_t)(nrow0 + row) * KTOT + ke),
                 (void*)(lb + 8192 + L * 16));
      load_lds16((const void*)(Btl + (size_t)(nrow0 + row) * KTOT + ke),
                 (void*)(lb + 16384 + L * 16));
    }
  };

  stage(0, 0);
  __syncthreads();
  const int l15 = lane & 15;
  const int lhi = lane >> 4;
  const int kb = lhi * 16;                              // byte offset of this lane's k-slot
  const int arow = wv * 16 + l15;
  const int aoff = arow * 64 + (kb ^ (((arow >> 2) & 3) << 4));

  for (int t = 0; t < ntiles; ++t) {
    int cur = t & 1;
    if (t + 1 < ntiles) stage(cur ^ 1, (t + 1) << 5);
    const char* base = smem + cur * 24576;
    short8 ah = *(const short8*)(base + aoff);
    short8 al = *(const short8*)(base + 4096 + aoff);
#pragma unroll
    for (int f = 0; f < 8; ++f) {
      int brow = f * 16 + l15;
      int boff = brow * 64 + (kb ^ (((brow >> 2) & 3) << 4));
      short8 bh = *(const short8*)(base + 8192 + boff);
      short8 bl = *(const short8*)(base + 16384 + boff);
      acc[f] = __builtin_amdgcn_mfma_f32_16x16x32_bf16(ah, bh, acc[f], 0, 0, 0);
      acc[f] = __builtin_amdgcn_mfma_f32_16x16x32_bf16(ah, bl, acc[f], 0, 0, 0);
      acc[f] = __builtin_amdgcn_mfma_f32_16x16x32_bf16(al, bh, acc[f], 0, 0, 0);
    }
    __syncthreads();
  }

  if (EPI == 0) {
#pragma unroll
    for (int s = 0; s < 2; ++s) {
      f32x4 ai = acc[0 + s], af = acc[2 + s], ag = acc[4 + s], ao = acc[6 + s];
      int unit = npanel * 32 + s * 16 + l15;
      int prb = npanel * 128 + s * 16 + l15;
      float bi = bias[prb + 0];
      float bfv = bias[prb + 32];
      float bg = bias[prb + 64];
      float bo = bias[prb + 96];
#pragma unroll
      for (int r = 0; r < 4; ++r) {
        int row = m0 + wv * 16 + lhi * 4 + r;
        float iv = ai[r] + bi;
        float fv = af[r] + bfv;
        float gv = ag[r] + bg;
        float ov = ao[r] + bo;
        size_t idx = (size_t)row * HH + unit;
        float co = cstate[idx];
        float cn2 = sigm(fv) * co + sigm(iv) * tanh_f(gv);
        cstate[idx] = cn2;
        float hv = sigm(ov) * tanh_f(cn2);
        bf16 hh = __float2bfloat16(hv);
        houth[idx] = hh;
        houtl[idx] = __float2bfloat16(hv - __bfloat162float(hh));
      }
    }
  } else {
#pragma unroll
    for (int f = 0; f < 8; ++f) {
      int col = npanel * 128 + f * 16 + l15;
      float bb = bias[col];
#pragma unroll
      for (int r = 0; r < 4; ++r) {
        int row = m0 + wv * 16 + lhi * 4 + r;
        zout[(size_t)row * HH + col] = acc[f][r] + bb;
      }
    }
  }
}

// ---------------- LayerNorm + ReLU + fc2 (f32) + output + feedback ----------------
__global__ __launch_bounds__(256) void ln_fc2_k(
    const float* __restrict__ z, const float* __restrict__ lng, const float* __restrict__ lnb,
    const float* __restrict__ W2 /*[1024][64]*/, const float* __restrict__ b2,
    float* __restrict__ out /*[512][96][64]*/,
    bf16* __restrict__ xbh, bf16* __restrict__ xbl, int tstep)
{
  __shared__ float sa[4][1024];
  __shared__ float red[4][4][64];
  int tid = threadIdx.x, lane = tid & 63, w = tid >> 6;
  int row = blockIdx.x * 4 + w;
  float zv[16];
#pragma unroll
  for (int j = 0; j < 16; ++j) zv[j] = z[(size_t)row * 1024 + j * 64 + lane];
  float s = 0;
#pragma unroll
  for (int j = 0; j < 16; ++j) s += zv[j];
  s = wred(s);
  float mu = s * (1.0f / 1024.0f);
  float vs = 0;
#pragma unroll
  for (int j = 0; j < 16; ++j) { float d = zv[j] - mu; vs += d * d; }
  vs = wred(vs);
  float rstd = rsqrtf(vs * (1.0f / 1024.0f) + 1e-5f);
#pragma unroll
  for (int j = 0; j < 16; ++j) {
    int k = j * 64 + lane;
    float a = (zv[j] - mu) * rstd * lng[k] + lnb[k];
    sa[w][k] = a > 0.0f ? a : 0.0f;
  }
  __syncthreads();
  int n = tid & 63, ks = (tid >> 6) * 256;
  float p0 = 0, p1 = 0, p2 = 0, p3 = 0;
  for (int k = ks; k < ks + 256; ++k) {
    float wv2 = W2[(size_t)k * 64 + n];
    p0 += sa[0][k] * wv2; p1 += sa[1][k] * wv2; p2 += sa[2][k] * wv2; p3 += sa[3][k] * wv2;
  }
  int sl = tid >> 6;
  red[0][sl][n] = p0; red[1][sl][n] = p1; red[2][sl][n] = p2; red[3][sl][n] = p3;
  __syncthreads();
  int rr = tid >> 6;
  float y = red[rr][0][n] + red[rr][1][n] + red[rr][2][n] + red[rr][3][n] + b2[n];
  int orow = blockIdx.x * 4 + rr;
  out[((size_t)orow * TT + tstep) * DD + n] = y;
  bf16 hh = __float2bfloat16(y);
  xbh[(size_t)orow * DD + n] = hh;
  xbl[(size_t)orow * DD + n] = __float2bfloat16(y - __bfloat162float(hh));
}

// ---------------- host ----------------

extern "C" void kernel_launch(void* const* d_in, const int* in_sizes, int n_in,
                              void* d_out, int out_size, void* d_ws, size_t ws_size,
                              hipStream_t stream)
{
  const float* x0   = (const float*)d_in[0];
  const float* hn   = (const float*)d_in[1];
  const float* cn   = (const float*)d_in[2];
  const float* embW = (const float*)d_in[4];
  const float* embB = (const float*)d_in[5];
  const float* Wih0 = (const float*)d_in[6];
  const float* Whh0 = (const float*)d_in[7];
  const float* bih0 = (const float*)d_in[8];
  const float* bhh0 = (const float*)d_in[9];
  const float* Wih1 = (const float*)d_in[10];
  const float* Whh1 = (const float*)d_in[11];
  const float* bih1 = (const float*)d_in[12];
  const float* bhh1 = (const float*)d_in[13];
  const float* fc1W = (const float*)d_in[14];
  const float* fc1b = (const float*)d_in[15];
  const float* lng  = (const float*)d_in[16];
  const float* lnb  = (const float*)d_in[17];
  const float* fc2W = (const float*)d_in[18];
  const float* fc2b = (const float*)d_in[19];

  char* wp = (char*)d_ws;
  size_t off = 0;
  auto alloc = [&](size_t bytes) -> void* {
    void* p = wp + off;
    off += (bytes + 255) & ~(size_t)255;
    return p;
  };

  bf16* W0th  = (bf16*)alloc((size_t)4096 * 1088 * 2);
  bf16* W0tl  = (bf16*)alloc((size_t)4096 * 1088 * 2);
  bf16* W1th  = (bf16*)alloc((size_t)4096 * 2048 * 2);
  bf16* W1tl  = (bf16*)alloc((size_t)4096 * 2048 * 2);
  bf16* f1h   = (bf16*)alloc((size_t)1024 * 1024 * 2);
  bf16* f1l   = (bf16*)alloc((size_t)1024 * 1024 * 2);
  float* bias0 = (float*)alloc(4096 * 4);
  float* bias1 = (float*)alloc(4096 * 4);
  bf16* xbh   = (bf16*)alloc((size_t)BB * DD * 2);
  bf16* xbl   = (bf16*)alloc((size_t)BB * DD * 2);
  bf16* h0h_a = (bf16*)alloc((size_t)BB * HH * 2);
  bf16* h0h_b = (bf16*)alloc((size_t)BB * HH * 2);
  bf16* h0l_a = (bf16*)alloc((size_t)BB * HH * 2);
  bf16* h0l_b = (bf16*)alloc((size_t)BB * HH * 2);
  bf16* h1h_a = (bf16*)alloc((size_t)BB * HH * 2);
  bf16* h1h_b = (bf16*)alloc((size_t)BB * HH * 2);
  bf16* h1l_a = (bf16*)alloc((size_t)BB * HH * 2);
  bf16* h1l_b = (bf16*)alloc((size_t)BB * HH * 2);
  float* c0   = (float*)alloc((size_t)BB * HH * 4);
  float* c1   = (float*)alloc((size_t)BB * HH * 4);
  float* z    = (float*)alloc((size_t)BB * HH * 4);

  init_states_k<<<2048, 256, 0, stream>>>(x0, hn, cn, xbh, xbl, h0h_a, h0l_a, h1h_a, h1l_a, c0, c1);
  fold_emb_k<<<dim3(16, 8), 256, 0, stream>>>(embW, embB, Wih0, bih0, bhh0, W0th, W0tl, bias0);
  transpose_conv_k<true><<<dim3(128, 32), 256, 0, stream>>>(Whh0, 4096, W0th, W0tl, 1088, 64);
  transpose_conv_k<true><<<dim3(128, 32), 256, 0, stream>>>(Wih1, 4096, W1th, W1tl, 2048, 0);
  transpose_conv_k<true><<<dim3(128, 32), 256, 0, stream>>>(Whh1, 4096, W1th, W1tl, 2048, 1024);
  transpose_conv_k<false><<<dim3(32, 32), 256, 0, stream>>>(fc1W, 1024, f1h, f1l, 1024, 0);
  bias_perm_k<<<16, 256, 0, stream>>>(bih1, bhh1, bias1);

  bf16* h0h[2] = {h0h_a, h0h_b};
  bf16* h0l[2] = {h0l_a, h0l_b};
  bf16* h1h[2] = {h1h_a, h1h_b};
  bf16* h1l[2] = {h1l_a, h1l_b};
  float* outp = (float*)d_out;

  for (int t = 0; t < TT; ++t) {
    int p = t & 1;
    // gates0 (+cell0): A = [x | h0_prev], K = 1088
    gemm_step_k<0><<<256, 256, 0, stream>>>(
        xbh, xbl, DD, DD, h0h[p], h0l[p], HH, W0th, W0tl, 1088, bias0,
        nullptr, c0, h0h[p ^ 1], h0l[p ^ 1], 32);
    // gates1 (+cell1): A = [h0_cur | h1_prev], K = 2048
    gemm_step_k<0><<<256, 256, 0, stream>>>(
        h0h[p ^ 1], h0l[p ^ 1], HH, HH, h1h[p], h1l[p], HH, W1th, W1tl, 2048, bias1,
        nullptr, c1, h1h[p ^ 1], h1l[p ^ 1], 32);
    // fc1: z = h1_cur @ fc1W + b, K = 1024
    gemm_step_k<1><<<64, 256, 0, stream>>>(
        h1h[p ^ 1], h1l[p ^ 1], HH, 1024, h1h[p ^ 1], h1l[p ^ 1], HH, f1h, f1l, 1024,
        fc1b, z, nullptr, nullptr, nullptr, 8);
    // LN + ReLU + fc2 (f32) + write out[:, t, :] + feedback x hi/lo
    ln_fc2_k<<<128, 256, 0, stream>>>(z, lng, lnb, fc2W, fc2b, outp, xbh, xbl, t);
  }
}

// Round 3
// 10663.290 us; speedup vs baseline: 1.0057x; 1.0057x over previous
//
#include <hip/hip_runtime.h>
#include <hip/hip_bf16.h>

using bf16 = __hip_bfloat16;
using short8 = __attribute__((ext_vector_type(8))) short;
using f32x4 = __attribute__((ext_vector_type(4))) float;

#define BB 512
#define HH 1024
#define DD 64
#define TT 96

__device__ __forceinline__ void load_lds16(const void* g, void* l) {
  __builtin_amdgcn_global_load_lds(
      (const __attribute__((address_space(1))) unsigned int*)g,
      (__attribute__((address_space(3))) unsigned int*)l, 16, 0, 0);
}

__device__ __forceinline__ float sigm(float x) { return 1.0f / (1.0f + __expf(-x)); }
__device__ __forceinline__ float tanh_f(float x) {
  float e = __expf(2.0f * x);
  return 1.0f - 2.0f / (e + 1.0f);
}
__device__ __forceinline__ float wred(float v) {
#pragma unroll
  for (int m = 1; m < 64; m <<= 1) v += __shfl_xor(v, m, 64);
  return v;
}

// ---------------- preprocessing kernels ----------------

__global__ __launch_bounds__(256) void init_states_k(
    const float* __restrict__ x0, const float* __restrict__ hn, const float* __restrict__ cn,
    bf16* __restrict__ xbh, bf16* __restrict__ xbl,
    bf16* __restrict__ h0h, bf16* __restrict__ h0l,
    bf16* __restrict__ h1h, bf16* __restrict__ h1l,
    float* __restrict__ c0, float* __restrict__ c1)
{
  int i = blockIdx.x * 256 + threadIdx.x;
  if (i < BB * HH) {
    float v0 = hn[i];
    bf16 a0 = __float2bfloat16(v0);
    h0h[i] = a0; h0l[i] = __float2bfloat16(v0 - __bfloat162float(a0));
    float v1 = hn[BB * HH + i];
    bf16 a1 = __float2bfloat16(v1);
    h1h[i] = a1; h1l[i] = __float2bfloat16(v1 - __bfloat162float(a1));
    c0[i] = cn[i];
    c1[i] = cn[BB * HH + i];
  }
  if (i < BB * DD) {
    float v = x0[i];
    bf16 a = __float2bfloat16(v);
    xbh[i] = a; xbl[i] = __float2bfloat16(v - __bfloat162float(a));
  }
}

// gate-row permutation: col c (= g*1024 + n) -> pr = (n>>5)*128 + g*32 + (n&31)
__device__ __forceinline__ int gate_perm(int c) {
  int g = c >> 10, n = c & 1023;
  return (n >> 5) * 128 + g * 32 + (n & 31);
}

// builds W0t rows for k<64 (folded emb_W @ W_ih0) + bias0
__global__ __launch_bounds__(256) void fold_emb_k(
    const float* __restrict__ embW, const float* __restrict__ embB,
    const float* __restrict__ Wih0, const float* __restrict__ bih0, const float* __restrict__ bhh0,
    bf16* __restrict__ W0h, bf16* __restrict__ W0l, float* __restrict__ bias0)
{
  __shared__ float sW[512 * 8];
  __shared__ float sb[512];
  int tid = threadIdx.x;
  int d0 = blockIdx.y * 8;
  for (int i = tid; i < 4096; i += 256) {
    int j = i >> 9;
    int e = i & 511;
    sW[e * 8 + j] = embW[(size_t)(d0 + j) * 512 + e];
  }
  for (int i = tid; i < 512; i += 256) sb[i] = embB[i];
  __syncthreads();
  int c = blockIdx.x * 256 + tid;  // 0..4095
  float acc[8] = {0, 0, 0, 0, 0, 0, 0, 0};
  float bacc = 0.0f;
  for (int e = 0; e < 512; ++e) {
    float wv = Wih0[(size_t)e * 4096 + c];
    float4 wa = *(const float4*)&sW[e * 8];
    float4 wb = *(const float4*)&sW[e * 8 + 4];
    acc[0] += wa.x * wv; acc[1] += wa.y * wv; acc[2] += wa.z * wv; acc[3] += wa.w * wv;
    acc[4] += wb.x * wv; acc[5] += wb.y * wv; acc[6] += wb.z * wv; acc[7] += wb.w * wv;
    bacc += sb[e] * wv;
  }
  int pr = gate_perm(c);
#pragma unroll
  for (int j = 0; j < 8; ++j) {
    float v = acc[j];
    bf16 h = __float2bfloat16(v);
    W0h[(size_t)pr * 1088 + d0 + j] = h;
    W0l[(size_t)pr * 1088 + d0 + j] = __float2bfloat16(v - __bfloat162float(h));
  }
  if (blockIdx.y == 0) bias0[pr] = bacc + bih0[c] + bhh0[c];
}

// src f32 [K][N] row-major -> dst bf16 hi/lo [perm(c)][dstStride] at col offset k0
template <bool PERM>
__global__ __launch_bounds__(256) void transpose_conv_k(
    const float* __restrict__ src, int N,
    bf16* __restrict__ dsth, bf16* __restrict__ dstl, int dstStride, int k0)
{
  __shared__ float tb[32][33];
  int tx = threadIdx.x & 31;
  int ty = threadIdx.x >> 5;  // 0..7
  int c0 = blockIdx.x * 32;
  int kk0 = blockIdx.y * 32;
#pragma unroll
  for (int q = 0; q < 4; ++q) {
    int k = kk0 + q * 8 + ty;
    tb[q * 8 + ty][tx] = src[(size_t)k * N + c0 + tx];
  }
  __syncthreads();
#pragma unroll
  for (int q = 0; q < 4; ++q) {
    int cc = c0 + q * 8 + ty;
    int pr = PERM ? gate_perm(cc) : cc;
    float v = tb[tx][q * 8 + ty];
    bf16 h = __float2bfloat16(v);
    size_t di = (size_t)pr * dstStride + k0 + kk0 + tx;
    dsth[di] = h;
    dstl[di] = __float2bfloat16(v - __bfloat162float(h));
  }
}

__global__ __launch_bounds__(256) void bias_perm_k(
    const float* __restrict__ a, const float* __restrict__ b, float* __restrict__ out)
{
  int c = blockIdx.x * 256 + threadIdx.x;
  out[gate_perm(c)] = a[c] + b[c];
}

// ---------------- main GEMM (+ optional LSTM-cell epilogue), hi/lo split ----------------
// C tile 32x128, 2 waves split-M (16x128 each), BK=32, dbuf LDS (40KB) -> 2 blocks/CU.
// acc += Ah*Bh + Ah*Bl + Al*Bh  (Al*Bl ~1.6e-5 rel, dropped).
// EPI==0: gate panel [i32|f32|g32|o32] of 32 units -> cell -> h hi/lo out, c inplace f32.
// EPI==1: f32 + bias -> zout.
template <int EPI>
__global__ __launch_bounds__(128) void gemm_step_k(
    const bf16* __restrict__ A1h, const bf16* __restrict__ A1l, int lda1, int K1len,
    const bf16* __restrict__ A2h, const bf16* __restrict__ A2l, int lda2,
    const bf16* __restrict__ Bth, const bf16* __restrict__ Btl, int KTOT,
    const float* __restrict__ bias,
    float* __restrict__ zout,
    float* __restrict__ cstate,
    bf16* __restrict__ houth, bf16* __restrict__ houtl,
    int nPanels)
{
  // per buffer: Ah 2K | Al 2K | Bh 8K | Bl 8K = 20KB; x2 buffers = 40KB
  __shared__ __align__(16) char smem[40960];
  const int tid = threadIdx.x;
  const int lane = tid & 63;
  const int wv = tid >> 6;   // 0..1
  const int bid = blockIdx.x;
  const int npanel = bid % nPanels;  // n fastest: same panel -> same XCD (nPanels % 8 == 0)
  const int m0 = (bid / nPanels) * 32;
  const int nrow0 = npanel * 128;

  f32x4 acc[8] = {};
  const int ntiles = KTOT >> 5;

  auto stage = [&](int qbuf, int kt) {
    char* lb = smem + qbuf * 20480;
    {
      int row = tid >> 2, sl = tid & 3;                 // A: 32 rows x 4 slots
      int sb = (sl * 16) ^ (((row >> 2) & 3) << 4);     // pre-swizzled source byte
      int ke = kt + (sb >> 1);
      const bf16 *gh, *gl;
      if (kt < K1len) {
        gh = A1h + (size_t)(m0 + row) * lda1 + ke;
        gl = A1l + (size_t)(m0 + row) * lda1 + ke;
      } else {
        gh = A2h + (size_t)(m0 + row) * lda2 + (ke - K1len);
        gl = A2l + (size_t)(m0 + row) * lda2 + (ke - K1len);
      }
      load_lds16((const void*)gh, (void*)(lb + tid * 16));
      load_lds16((const void*)gl, (void*)(lb + 2048 + tid * 16));
    }
#pragma unroll
    for (int q = 0; q < 4; ++q) {                       // B: 128 rows x 4 slots
      int L = q * 128 + tid;
      int row = L >> 2, sl = L & 3;
      int sb = (sl * 16) ^ (((row >> 2) & 3) << 4);
      int ke = kt + (sb >> 1);
      load_lds16((const void*)(Bth + (size_t)(nrow0 + row) * KTOT + ke),
                 (void*)(lb + 4096 + L * 16));
      load_lds16((const void*)(Btl + (size_t)(nrow0 + row) * KTOT + ke),
                 (void*)(lb + 12288 + L * 16));
    }
  };

  stage(0, 0);
  __syncthreads();
  const int l15 = lane & 15;
  const int lhi = lane >> 4;
  const int kb = lhi * 16;                              // byte offset of this lane's k-slot
  const int arow = wv * 16 + l15;
  const int aoff = arow * 64 + (kb ^ (((arow >> 2) & 3) << 4));

  for (int t = 0; t < ntiles; ++t) {
    int cur = t & 1;
    if (t + 1 < ntiles) stage(cur ^ 1, (t + 1) << 5);
    const char* base = smem + cur * 20480;
    short8 ah = *(const short8*)(base + aoff);
    short8 al = *(const short8*)(base + 2048 + aoff);
#pragma unroll
    for (int f = 0; f < 8; ++f) {
      int brow = f * 16 + l15;
      int boff = brow * 64 + (kb ^ (((brow >> 2) & 3) << 4));
      short8 bh = *(const short8*)(base + 4096 + boff);
      short8 bl = *(const short8*)(base + 12288 + boff);
      acc[f] = __builtin_amdgcn_mfma_f32_16x16x32_bf16(ah, bh, acc[f], 0, 0, 0);
      acc[f] = __builtin_amdgcn_mfma_f32_16x16x32_bf16(ah, bl, acc[f], 0, 0, 0);
      acc[f] = __builtin_amdgcn_mfma_f32_16x16x32_bf16(al, bh, acc[f], 0, 0, 0);
    }
    __syncthreads();
  }

  if (EPI == 0) {
#pragma unroll
    for (int s = 0; s < 2; ++s) {
      f32x4 ai = acc[0 + s], af = acc[2 + s], ag = acc[4 + s], ao = acc[6 + s];
      int unit = npanel * 32 + s * 16 + l15;
      int prb = npanel * 128 + s * 16 + l15;
      float bi = bias[prb + 0];
      float bfv = bias[prb + 32];
      float bg = bias[prb + 64];
      float bo = bias[prb + 96];
#pragma unroll
      for (int r = 0; r < 4; ++r) {
        int row = m0 + wv * 16 + lhi * 4 + r;
        float iv = ai[r] + bi;
        float fv = af[r] + bfv;
        float gv = ag[r] + bg;
        float ov = ao[r] + bo;
        size_t idx = (size_t)row * HH + unit;
        float co = cstate[idx];
        float cn2 = sigm(fv) * co + sigm(iv) * tanh_f(gv);
        cstate[idx] = cn2;
        float hv = sigm(ov) * tanh_f(cn2);
        bf16 hh = __float2bfloat16(hv);
        houth[idx] = hh;
        houtl[idx] = __float2bfloat16(hv - __bfloat162float(hh));
      }
    }
  } else {
#pragma unroll
    for (int f = 0; f < 8; ++f) {
      int col = npanel * 128 + f * 16 + l15;
      float bb = bias[col];
#pragma unroll
      for (int r = 0; r < 4; ++r) {
        int row = m0 + wv * 16 + lhi * 4 + r;
        zout[(size_t)row * HH + col] = acc[f][r] + bb;
      }
    }
  }
}

// ---------------- LayerNorm + ReLU + fc2 (f32) + output + feedback ----------------
__global__ __launch_bounds__(256) void ln_fc2_k(
    const float* __restrict__ z, const float* __restrict__ lng, const float* __restrict__ lnb,
    const float* __restrict__ W2 /*[1024][64]*/, const float* __restrict__ b2,
    float* __restrict__ out /*[512][96][64]*/,
    bf16* __restrict__ xbh, bf16* __restrict__ xbl, int tstep)
{
  __shared__ float sa[4][1024];
  __shared__ float red[4][4][64];
  int tid = threadIdx.x, lane = tid & 63, w = tid >> 6;
  int row = blockIdx.x * 4 + w;
  float zv[16];
#pragma unroll
  for (int j = 0; j < 16; ++j) zv[j] = z[(size_t)row * 1024 + j * 64 + lane];
  float s = 0;
#pragma unroll
  for (int j = 0; j < 16; ++j) s += zv[j];
  s = wred(s);
  float mu = s * (1.0f / 1024.0f);
  float vs = 0;
#pragma unroll
  for (int j = 0; j < 16; ++j) { float d = zv[j] - mu; vs += d * d; }
  vs = wred(vs);
  float rstd = rsqrtf(vs * (1.0f / 1024.0f) + 1e-5f);
#pragma unroll
  for (int j = 0; j < 16; ++j) {
    int k = j * 64 + lane;
    float a = (zv[j] - mu) * rstd * lng[k] + lnb[k];
    sa[w][k] = a > 0.0f ? a : 0.0f;
  }
  __syncthreads();
  int n = tid & 63, ks = (tid >> 6) * 256;
  float p0 = 0, p1 = 0, p2 = 0, p3 = 0;
  for (int k = ks; k < ks + 256; ++k) {
    float wv2 = W2[(size_t)k * 64 + n];
    p0 += sa[0][k] * wv2; p1 += sa[1][k] * wv2; p2 += sa[2][k] * wv2; p3 += sa[3][k] * wv2;
  }
  int sl = tid >> 6;
  red[0][sl][n] = p0; red[1][sl][n] = p1; red[2][sl][n] = p2; red[3][sl][n] = p3;
  __syncthreads();
  int rr = tid >> 6;
  float y = red[rr][0][n] + red[rr][1][n] + red[rr][2][n] + red[rr][3][n] + b2[n];
  int orow = blockIdx.x * 4 + rr;
  out[((size_t)orow * TT + tstep) * DD + n] = y;
  bf16 hh = __float2bfloat16(y);
  xbh[(size_t)orow * DD + n] = hh;
  xbl[(size_t)orow * DD + n] = __float2bfloat16(y - __bfloat162float(hh));
}

// ---------------- host ----------------

extern "C" void kernel_launch(void* const* d_in, const int* in_sizes, int n_in,
                              void* d_out, int out_size, void* d_ws, size_t ws_size,
                              hipStream_t stream)
{
  const float* x0   = (const float*)d_in[0];
  const float* hn   = (const float*)d_in[1];
  const float* cn   = (const float*)d_in[2];
  const float* embW = (const float*)d_in[4];
  const float* embB = (const float*)d_in[5];
  const float* Wih0 = (const float*)d_in[6];
  const float* Whh0 = (const float*)d_in[7];
  const float* bih0 = (const float*)d_in[8];
  const float* bhh0 = (const float*)d_in[9];
  const float* Wih1 = (const float*)d_in[10];
  const float* Whh1 = (const float*)d_in[11];
  const float* bih1 = (const float*)d_in[12];
  const float* bhh1 = (const float*)d_in[13];
  const float* fc1W = (const float*)d_in[14];
  const float* fc1b = (const float*)d_in[15];
  const float* lng  = (const float*)d_in[16];
  const float* lnb  = (const float*)d_in[17];
  const float* fc2W = (const float*)d_in[18];
  const float* fc2b = (const float*)d_in[19];

  char* wp = (char*)d_ws;
  size_t off = 0;
  auto alloc = [&](size_t bytes) -> void* {
    void* p = wp + off;
    off += (bytes + 255) & ~(size_t)255;
    return p;
  };

  bf16* W0th  = (bf16*)alloc((size_t)4096 * 1088 * 2);
  bf16* W0tl  = (bf16*)alloc((size_t)4096 * 1088 * 2);
  bf16* W1th  = (bf16*)alloc((size_t)4096 * 2048 * 2);
  bf16* W1tl  = (bf16*)alloc((size_t)4096 * 2048 * 2);
  bf16* f1h   = (bf16*)alloc((size_t)1024 * 1024 * 2);
  bf16* f1l   = (bf16*)alloc((size_t)1024 * 1024 * 2);
  float* bias0 = (float*)alloc(4096 * 4);
  float* bias1 = (float*)alloc(4096 * 4);
  bf16* xbh   = (bf16*)alloc((size_t)BB * DD * 2);
  bf16* xbl   = (bf16*)alloc((size_t)BB * DD * 2);
  bf16* h0h_a = (bf16*)alloc((size_t)BB * HH * 2);
  bf16* h0h_b = (bf16*)alloc((size_t)BB * HH * 2);
  bf16* h0l_a = (bf16*)alloc((size_t)BB * HH * 2);
  bf16* h0l_b = (bf16*)alloc((size_t)BB * HH * 2);
  bf16* h1h_a = (bf16*)alloc((size_t)BB * HH * 2);
  bf16* h1h_b = (bf16*)alloc((size_t)BB * HH * 2);
  bf16* h1l_a = (bf16*)alloc((size_t)BB * HH * 2);
  bf16* h1l_b = (bf16*)alloc((size_t)BB * HH * 2);
  float* c0   = (float*)alloc((size_t)BB * HH * 4);
  float* c1   = (float*)alloc((size_t)BB * HH * 4);
  float* z    = (float*)alloc((size_t)BB * HH * 4);

  init_states_k<<<2048, 256, 0, stream>>>(x0, hn, cn, xbh, xbl, h0h_a, h0l_a, h1h_a, h1l_a, c0, c1);
  fold_emb_k<<<dim3(16, 8), 256, 0, stream>>>(embW, embB, Wih0, bih0, bhh0, W0th, W0tl, bias0);
  transpose_conv_k<true><<<dim3(128, 32), 256, 0, stream>>>(Whh0, 4096, W0th, W0tl, 1088, 64);
  transpose_conv_k<true><<<dim3(128, 32), 256, 0, stream>>>(Wih1, 4096, W1th, W1tl, 2048, 0);
  transpose_conv_k<true><<<dim3(128, 32), 256, 0, stream>>>(Whh1, 4096, W1th, W1tl, 2048, 1024);
  transpose_conv_k<false><<<dim3(32, 32), 256, 0, stream>>>(fc1W, 1024, f1h, f1l, 1024, 0);
  bias_perm_k<<<16, 256, 0, stream>>>(bih1, bhh1, bias1);

  bf16* h0h[2] = {h0h_a, h0h_b};
  bf16* h0l[2] = {h0l_a, h0l_b};
  bf16* h1h[2] = {h1h_a, h1h_b};
  bf16* h1l[2] = {h1l_a, h1l_b};
  float* outp = (float*)d_out;

  for (int t = 0; t < TT; ++t) {
    int p = t & 1;
    // gates0 (+cell0): A = [x | h0_prev], K = 1088; grid 16m x 32n = 512 blocks (2/CU)
    gemm_step_k<0><<<512, 128, 0, stream>>>(
        xbh, xbl, DD, DD, h0h[p], h0l[p], HH, W0th, W0tl, 1088, bias0,
        nullptr, c0, h0h[p ^ 1], h0l[p ^ 1], 32);
    // gates1 (+cell1): A = [h0_cur | h1_prev], K = 2048
    gemm_step_k<0><<<512, 128, 0, stream>>>(
        h0h[p ^ 1], h0l[p ^ 1], HH, HH, h1h[p], h1l[p], HH, W1th, W1tl, 2048, bias1,
        nullptr, c1, h1h[p ^ 1], h1l[p ^ 1], 32);
    // fc1: z = h1_cur @ fc1W + b, K = 1024; grid 16m x 8n = 128 blocks
    gemm_step_k<1><<<128, 128, 0, stream>>>(
        h1h[p ^ 1], h1l[p ^ 1], HH, 1024, h1h[p ^ 1], h1l[p ^ 1], HH, f1h, f1l, 1024,
        fc1b, z, nullptr, nullptr, nullptr, 8);
    // LN + ReLU + fc2 (f32) + write out[:, t, :] + feedback x hi/lo
    ln_fc2_k<<<128, 256, 0, stream>>>(z, lng, lnb, fc2W, fc2b, outp, xbh, xbl, t);
  }
}